// Round 18
// baseline (3682.828 us; speedup 1.0000x reference)
//
#include <hip/hip_runtime.h>
#include <hip/hip_bf16.h>

#define HDIM 300
#define FEAT 16
#define NL 5
#define BGR 4096
#define BNEPS 1e-5f
#define KP1 320   // K=300 padded to multiple of 32
#define KP2 640   // K=600 padded to multiple of 32

typedef __attribute__((ext_vector_type(8))) short s8v;
typedef __attribute__((ext_vector_type(4))) float f4v;
typedef __attribute__((ext_vector_type(2))) _Float16 h2v;
typedef __attribute__((ext_vector_type(8))) _Float16 h8v;

__device__ __forceinline__ unsigned short f2bu(float f){
    __hip_bfloat16 h = __float2bfloat16(f);
    return __builtin_bit_cast(unsigned short, h);
}
__device__ __forceinline__ h2v u2h(unsigned int u){
    return __builtin_bit_cast(h2v, u);
}
// fp16-pair dot with f32 accumulate: one v_dot2_f32_f16 instead of two fma_mix
__device__ __forceinline__ float dot2f(h2v a, h2v b, float c){
#if __has_builtin(__builtin_amdgcn_fdot2)
    return __builtin_amdgcn_fdot2(a, b, c, false);
#else
    return fmaf((float)a.x, (float)b.x, fmaf((float)a.y, (float)b.y, c));
#endif
}

// ---------------- setup kernels ----------------
__global__ void k_count_deg(const int* __restrict__ dst, int* __restrict__ cnt, int E){
    int e = blockIdx.x*blockDim.x + threadIdx.x;
    if (e < E) atomicAdd(&cnt[dst[e]], 1);
}
__global__ void k_deg(const int* __restrict__ cnt, float* __restrict__ degs,
                      float* __restrict__ invd, int N){
    int i = blockIdx.x*blockDim.x + threadIdx.x;
    if (i < N){
        float d = (float)cnt[i] + 1.0f;
        degs[i] = d;
        invd[i] = 1.0f / d;
    }
}
// --- exclusive scan of cnt -> off (off[N]=E), 3 phases ---
__global__ void k_scan_partial(const int* __restrict__ cnt, int* __restrict__ part, int N){
    __shared__ int sm[256];
    int i = blockIdx.x*256 + threadIdx.x;
    sm[threadIdx.x] = (i < N) ? cnt[i] : 0;
    __syncthreads();
    for (int s = 128; s > 0; s >>= 1){
        if (threadIdx.x < s) sm[threadIdx.x] += sm[threadIdx.x + s];
        __syncthreads();
    }
    if (threadIdx.x == 0) part[blockIdx.x] = sm[0];
}
__global__ void k_scan_blocks(int* __restrict__ part, int nb){
    __shared__ int sm[512];
    int t = threadIdx.x;
    int v = (t < nb) ? part[t] : 0;
    sm[t] = v; __syncthreads();
    for (int o = 1; o < 512; o <<= 1){
        int x = (t >= o) ? sm[t - o] : 0;
        __syncthreads();
        sm[t] += x;
        __syncthreads();
    }
    if (t < nb) part[t] = sm[t] - v;   // exclusive
}
__global__ void k_scan_final(const int* __restrict__ cnt, const int* __restrict__ part,
                             int* __restrict__ off, int N){
    __shared__ int sm[256];
    int i = blockIdx.x*256 + threadIdx.x;
    int v = (i < N) ? cnt[i] : 0;
    sm[threadIdx.x] = v; __syncthreads();
    for (int o = 1; o < 256; o <<= 1){
        int x = (threadIdx.x >= o) ? sm[threadIdx.x - o] : 0;
        __syncthreads();
        sm[threadIdx.x] += x;
        __syncthreads();
    }
    if (i < N){
        off[i] = part[blockIdx.x] + sm[threadIdx.x] - v;
        if (i == N-1) off[N] = part[blockIdx.x] + sm[threadIdx.x];
    }
}
__global__ void k_fill(const int* __restrict__ dst, const int* __restrict__ off,
                       int* __restrict__ fillc, int* __restrict__ eid, int E){
    int e = blockIdx.x*blockDim.x + threadIdx.x;
    if (e < E){
        int d = dst[e];
        int p = off[d] + atomicAdd(&fillc[d], 1);
        eid[p] = e;
    }
}
// permute edge data into CSR (dst-grouped) order:
//   eaux[p] = {src, rsqrt(deg[src]*deg[dst]) as bits}
//   efph[p][k] = fp16(edge_feats[e][k])  (32B per edge)
__global__ void k_permute(const int* __restrict__ eid, const int* __restrict__ src,
                          const int* __restrict__ dst, const float* __restrict__ degs,
                          const float* __restrict__ ef,
                          int2* __restrict__ eaux, h2v* __restrict__ efph, int E){
    int p = blockIdx.x*blockDim.x + threadIdx.x;
    if (p >= E) return;
    int e = eid[p];
    int s = src[e];
    float n = rsqrtf(degs[s]*degs[dst[e]]);
    eaux[p] = make_int2(s, __float_as_int(n));
    const float4* s4 = (const float4*)(ef + (size_t)e*FEAT);
    float4 A = s4[0], B = s4[1], C = s4[2], D = s4[3];
    h2v* op = efph + (size_t)p*8;
    op[0] = (h2v){(_Float16)A.x, (_Float16)A.y};
    op[1] = (h2v){(_Float16)A.z, (_Float16)A.w};
    op[2] = (h2v){(_Float16)B.x, (_Float16)B.y};
    op[3] = (h2v){(_Float16)B.z, (_Float16)B.w};
    op[4] = (h2v){(_Float16)C.x, (_Float16)C.y};
    op[5] = (h2v){(_Float16)C.z, (_Float16)C.w};
    op[6] = (h2v){(_Float16)D.x, (_Float16)D.y};
    op[7] = (h2v){(_Float16)D.z, (_Float16)D.w};
}
// pack We (all layers) to fp16 pairs: Weh[(l*HDIM + c)*8 + kk] = {We[l][2kk][c], We[l][2kk+1][c]}
__global__ void k_wehalf(const float* __restrict__ We, h2v* __restrict__ Weh, int total){
    int t = blockIdx.x*blockDim.x + threadIdx.x;
    if (t >= total) return;
    int kk = t & 7;
    int lc = t >> 3;
    int c = lc % HDIM;
    int l = lc / HDIM;
    const float* w = We + (size_t)l*FEAT*HDIM;
    Weh[t] = (h2v){(_Float16)w[(size_t)(2*kk)*HDIM + c], (_Float16)w[(size_t)(2*kk+1)*HDIM + c]};
}
// gid is sorted: gstart[g] = first node index with gid >= g ; gstart[B] = N
__global__ void k_gstart(const int* __restrict__ gid, int* __restrict__ gstart, int N, int B){
    int i = blockIdx.x*blockDim.x + threadIdx.x;
    if (i >= N) return;
    int prev = (i == 0) ? -1 : gid[i-1];
    int cur = gid[i];
    for (int g = prev + 1; g <= cur; g++) gstart[g] = i;
    if (i == N-1) for (int g = cur + 1; g <= B; g++) gstart[g] = N;
}
// weight transpose+pad to bf16: Wt[n][kp] = W[k][n]  (W is K x Ncol row-major)
__global__ void k_wt(const float* __restrict__ W, unsigned short* __restrict__ Wt,
                     int K, int Ncol, int Kpad){
    int t = blockIdx.x*blockDim.x + threadIdx.x;
    if (t >= Ncol*Kpad) return;
    int n = t / Kpad, kp = t - n*Kpad;
    Wt[t] = (kp < K) ? f2bu(W[(size_t)kp*Ncol + n]) : (unsigned short)0;
}
// weight transpose+pad to fp16 (vnode layers>=1: needs 11-bit mantissa, bf16 fails tolerance)
__global__ void k_wt16(const float* __restrict__ W, _Float16* __restrict__ Wt,
                       int K, int Ncol, int Kpad){
    int t = blockIdx.x*blockDim.x + threadIdx.x;
    if (t >= Ncol*Kpad) return;
    int n = t / Kpad, kp = t - n*Kpad;
    Wt[t] = (kp < K) ? (_Float16)W[(size_t)kp*Ncol + n] : (_Float16)0.f;
}

// ---------------- FUSED layer-0 X build + segment sum (per-graph blocks) ----------------
__global__ void k_x0seg(const float* __restrict__ emb, const int* __restrict__ nt,
                        const float* __restrict__ vn, const int* __restrict__ gstart,
                        unsigned short* __restrict__ Xb,
                        float* __restrict__ vsum, _Float16* __restrict__ vsumh){
    int g = blockIdx.x;
    int c = threadIdx.x;
    if (c >= KP1) return;
    int r0 = gstart[g], r1 = gstart[g+1];
    if (c >= HDIM){
        for (int r = r0; r < r1; ++r) Xb[(size_t)r*KP1 + c] = 0;
        vsumh[(size_t)g*KP1 + c] = (_Float16)0.f;
        return;
    }
    float vf = vn[c];
    float s = 0.f;
    for (int r = r0; r < r1; ++r){
        float v = emb[(size_t)nt[r]*HDIM + c] + vf;
        Xb[(size_t)r*KP1 + c] = f2bu(v);
        s += v;
    }
    float t = s + vf;
    vsum[(size_t)g*HDIM + c] = t;
    vsumh[(size_t)g*KP1 + c] = (_Float16)t;
}

// ---------------- FUSED mid-layer BN+vfeat + segment sum (fp16 agg input) ----------------
__global__ void k_bnvseg(const _Float16* __restrict__ agg, const float* __restrict__ ss,
                         const float* __restrict__ vfeat, const int* __restrict__ gstart,
                         unsigned short* __restrict__ Xb,
                         _Float16* __restrict__ vsumh, int writeV){
    int g = blockIdx.x;
    int c = threadIdx.x;
    if (c >= KP1) return;
    int r0 = gstart[g], r1 = gstart[g+1];
    if (c >= HDIM){
        for (int r = r0; r < r1; ++r) Xb[(size_t)r*KP1 + c] = 0;
        if (writeV) vsumh[(size_t)g*KP1 + c] = (_Float16)0.f;
        return;
    }
    float sc = ss[c], sb = ss[HDIM + c];
    float vf = vfeat[(size_t)g*HDIM + c];
    float s = 0.f;
    for (int r = r0; r < r1; ++r){
        float v = fmaxf((float)agg[(size_t)r*HDIM + c]*sc + sb, 0.f) + vf;
        Xb[(size_t)r*KP1 + c] = f2bu(v);
        s += v;
    }
    if (writeV) vsumh[(size_t)g*KP1 + c] = (_Float16)(s + vf);
}

// ---------------- MFMA bf16 GEMM v4 (main path -> fp16 hp) ----------------
// 1D grid + bijective XCD-chunked swizzle (m204): all 5 col-tiles of a row-tile
// on the SAME XCD L2 -> A-tile fetched once. (Round-15: confirmed win.)
__global__ __launch_bounds__(256) void k_gemm_mfma(
    const unsigned short* __restrict__ A, int lda,
    const unsigned short* __restrict__ Wt, int ldw,
    const float* __restrict__ bias,
    _Float16* __restrict__ C, int M, int Kpad, int Ncol, int nbx)
{
    __shared__ short As[2][128][44];
    __shared__ short Bs[2][64][44];
    int tid = threadIdx.x;
    int nwg = gridDim.x;
    int q = nwg >> 3, r = nwg & 7;
    int orig = blockIdx.x;
    int xcd = orig & 7;
    int idx = orig >> 3;
    int lid = (xcd < r ? xcd*(q+1) : r*(q+1) + (xcd - r)*q) + idx;
    int bm = (lid / nbx) * 128;
    int bn = (lid % nbx) * 64;
    int lane = tid & 63;
    int w = tid >> 6;
    int wm = w & 1, wn = w >> 1;
    int l15 = lane & 15, l4 = lane >> 4;
    f4v acc[4][2];
#pragma unroll
    for (int mi = 0; mi < 4; mi++)
#pragma unroll
        for (int ni = 0; ni < 2; ni++) acc[mi][ni] = (f4v){0.f,0.f,0.f,0.f};

    int arow = tid >> 1;
    int akc  = (tid & 1) * 2;
    int gmA  = bm + arow;
    int brow = tid >> 2;
    int bkc  = tid & 3;
    int gnB  = bn + brow;
    const s8v zv = (s8v){0,0,0,0,0,0,0,0};
    int nT = Kpad / 32;

    auto loadT = [&](int k0, s8v& a0, s8v& a1, s8v& b0){
        a0 = zv; a1 = zv; b0 = zv;
        if (gmA < M){
            const s8v* ap = (const s8v*)(A + (size_t)gmA*lda + k0 + akc*8);
            a0 = ap[0]; a1 = ap[1];
        }
        if (gnB < Ncol) b0 = *(const s8v*)(Wt + (size_t)gnB*ldw + k0 + bkc*8);
    };
    auto storeT = [&](int buf, s8v a0, s8v a1, s8v b0){
        *(s8v*)&As[buf][arow][akc*8]     = a0;
        *(s8v*)&As[buf][arow][akc*8 + 8] = a1;
        *(s8v*)&Bs[buf][brow][bkc*8] = b0;
    };

    s8v a0, a1, b0;
    loadT(0, a0, a1, b0);
    storeT(0, a0, a1, b0);
    __syncthreads();

    int cur = 0;
    for (int t = 0; t < nT; ++t){
        if (t + 1 < nT) loadT((t+1)*32, a0, a1, b0);
        s8v af[4], bf[2];
#pragma unroll
        for (int mi = 0; mi < 4; mi++) af[mi] = *(const s8v*)&As[cur][wm*64 + mi*16 + l15][l4*8];
#pragma unroll
        for (int ni = 0; ni < 2; ni++) bf[ni] = *(const s8v*)&Bs[cur][wn*32 + ni*16 + l15][l4*8];
#pragma unroll
        for (int mi = 0; mi < 4; mi++)
#pragma unroll
            for (int ni = 0; ni < 2; ni++)
                acc[mi][ni] = __builtin_amdgcn_mfma_f32_16x16x32_bf16(af[mi], bf[ni], acc[mi][ni], 0, 0, 0);
        if (t + 1 < nT) storeT(cur ^ 1, a0, a1, b0);
        __syncthreads();
        cur ^= 1;
    }

#pragma unroll
    for (int ni = 0; ni < 2; ni++){
        int col = bn + wn*32 + ni*16 + l15;
        if (col >= Ncol) continue;
        float bia = bias[col];
#pragma unroll
        for (int mi = 0; mi < 4; mi++){
#pragma unroll
            for (int r2 = 0; r2 < 4; r2++){
                int row = bm + wm*64 + mi*16 + l4*4 + r2;
                if (row < M) C[(size_t)row*Ncol + col] = (_Float16)(acc[mi][ni][r2] + bia);
            }
        }
    }
}

// ---------------- MFMA fp16 GEMM (vnode layers>=1): C = A@Wt^T + bias ----------------
__global__ __launch_bounds__(256) void k_gemm_mfma_h(
    const _Float16* __restrict__ A, int lda,
    const _Float16* __restrict__ Wt, int ldw,
    const float* __restrict__ bias,
    float* __restrict__ C, int M, int Kpad, int Ncol)
{
    __shared__ _Float16 As[128][44];
    __shared__ _Float16 Bs[64][44];
    int tid = threadIdx.x;
    int bm = blockIdx.x * 128;
    int bn = blockIdx.y * 64;
    int lane = tid & 63;
    int w = tid >> 6;
    int wm = w & 1, wn = w >> 1;
    int l15 = lane & 15, l4 = lane >> 4;
    f4v acc[4][2];
#pragma unroll
    for (int mi = 0; mi < 4; mi++)
#pragma unroll
        for (int ni = 0; ni < 2; ni++) acc[mi][ni] = (f4v){0.f,0.f,0.f,0.f};

    int arow = tid >> 1;
    int akc  = (tid & 1) * 2;
    int gmA  = bm + arow;
    int brow = tid >> 2;
    int bkc  = tid & 3;
    int gnB  = bn + brow;
    const h8v zv = (h8v){0,0,0,0,0,0,0,0};

    for (int k0 = 0; k0 < Kpad; k0 += 32){
        __syncthreads();
        h8v a0 = zv, a1 = zv;
        if (gmA < M){
            const h8v* ap = (const h8v*)(A + (size_t)gmA*lda + k0 + akc*8);
            a0 = ap[0]; a1 = ap[1];
        }
        *(h8v*)&As[arow][akc*8]     = a0;
        *(h8v*)&As[arow][akc*8 + 8] = a1;
        h8v b0 = zv;
        if (gnB < Ncol) b0 = *(const h8v*)(Wt + (size_t)gnB*ldw + k0 + bkc*8);
        *(h8v*)&Bs[brow][bkc*8] = b0;
        __syncthreads();

        h8v af[4], bf[2];
#pragma unroll
        for (int mi = 0; mi < 4; mi++) af[mi] = *(const h8v*)&As[wm*64 + mi*16 + l15][l4*8];
#pragma unroll
        for (int ni = 0; ni < 2; ni++) bf[ni] = *(const h8v*)&Bs[wn*32 + ni*16 + l15][l4*8];
#pragma unroll
        for (int mi = 0; mi < 4; mi++)
#pragma unroll
            for (int ni = 0; ni < 2; ni++)
                acc[mi][ni] = __builtin_amdgcn_mfma_f32_16x16x32_f16(af[mi], bf[ni], acc[mi][ni], 0, 0, 0);
    }

#pragma unroll
    for (int ni = 0; ni < 2; ni++){
        int col = bn + wn*32 + ni*16 + l15;
        if (col >= Ncol) continue;
        float bia = bias[col];
#pragma unroll
        for (int mi = 0; mi < 4; mi++){
#pragma unroll
            for (int r = 0; r < 4; r++){
                int row = bm + wm*64 + mi*16 + l4*4 + r;
                if (row < M) C[(size_t)row*Ncol + col] = acc[mi][ni][r] + bia;
            }
        }
    }
}

// ---------------- f32 VALU GEMM v2 (layer-0 vnode path ONLY: precision-critical) ----------------
__global__ __launch_bounds__(256) void k_gemm(const float* __restrict__ A, const float* __restrict__ W,
                                              const float* __restrict__ bias, float* __restrict__ C,
                                              int M, int K, int Ncol){
    __shared__ float As[2][16][68];
    __shared__ float Ws[2][16][68];
    int tid = threadIdx.x;
    int bm = blockIdx.x * 64;
    int bn = blockIdx.y * 64;
    int tx = tid & 15;          // col group (4 cols)
    int ty = tid >> 4;          // row group (4 rows)
    float acc[4][4];
#pragma unroll
    for (int i = 0; i < 4; i++)
#pragma unroll
        for (int j = 0; j < 4; j++) acc[i][j] = 0.f;

    int ka  = tid & 15;
    int ra0 = tid >> 4;
    int colw = tid & 63;
    int kw0  = tid >> 6;
    int nT = (K + 15) / 16;

    auto loadA = [&](int k0, float av[4]){
#pragma unroll
        for (int j = 0; j < 4; j++){
            int gm = bm + ra0 + j*16, gk = k0 + ka;
            av[j] = (gm < M && gk < K) ? A[(size_t)gm*K + gk] : 0.f;
        }
    };
    auto loadW = [&](int k0, float wv[4]){
#pragma unroll
        for (int j = 0; j < 4; j++){
            int gk = k0 + kw0 + j*4, gn = bn + colw;
            wv[j] = (gk < K && gn < Ncol) ? W[(size_t)gk*Ncol + gn] : 0.f;
        }
    };
    auto storeT = [&](int buf, const float av[4], const float wv[4]){
#pragma unroll
        for (int j = 0; j < 4; j++) As[buf][ka][ra0 + j*16] = av[j];
#pragma unroll
        for (int j = 0; j < 4; j++) Ws[buf][kw0 + j*4][colw] = wv[j];
    };

    float av[4], wv[4];
    loadA(0, av); loadW(0, wv);
    storeT(0, av, wv);
    __syncthreads();

    int cur = 0;
    for (int t = 0; t < nT; ++t){
        if (t + 1 < nT){ loadA((t+1)*16, av); loadW((t+1)*16, wv); }
#pragma unroll
        for (int kk = 0; kk < 16; kk++){
            float a[4], b[4];
#pragma unroll
            for (int i = 0; i < 4; i++) a[i] = As[cur][kk][ty*4 + i];
#pragma unroll
            for (int j = 0; j < 4; j++) b[j] = Ws[cur][kk][tx*4 + j];
#pragma unroll
            for (int i = 0; i < 4; i++)
#pragma unroll
                for (int j = 0; j < 4; j++) acc[i][j] += a[i]*b[j];
        }
        if (t + 1 < nT) storeT(cur ^ 1, av, wv);
        __syncthreads();
        cur ^= 1;
    }

    float bb[4];
#pragma unroll
    for (int j = 0; j < 4; j++){ int gn = bn + tx*4 + j; bb[j] = (gn < Ncol) ? bias[gn] : 0.f; }
#pragma unroll
    for (int i = 0; i < 4; i++){
        int gm = bm + ty*4 + i;
        if (gm < M){
#pragma unroll
            for (int j = 0; j < 4; j++){
                int gn = bn + tx*4 + j;
                if (gn < Ncol) C[(size_t)gm*Ncol + gn] = acc[i][j] + bb[j];
            }
        }
    }
}

// ---------------- CSR aggregation v8: (256,8) occupancy bump ----------------
// v7 counters: VGPR=60, Occ=33%, VALU=43%, HBM 39% -- latency-bound, nothing
// saturated. Natural usage 60 fits the 64-VGPR budget of 8 waves/SIMD (unlike
// round-1 where ~85 VGPR of live state spilled under the same bound).
// out[d] = relu(hp[d]+res)*invd[d] + sum_p norm_p * relu(hp[src_p] + ef_p@We + be)
__global__ __launch_bounds__(256, 8) void k_agg(
    const _Float16* __restrict__ hp, const float* __restrict__ res,
    const float* __restrict__ invd,
    const h2v* __restrict__ efph, const int2* __restrict__ eaux,
    const int* __restrict__ off,
    const h2v* __restrict__ Weh, const float* __restrict__ be,
    _Float16* __restrict__ outh, float* __restrict__ outf, int useH, int N)
{
    int lane = threadIdx.x & 63;
    int wid  = blockIdx.x*4 + (threadIdx.x >> 6);
    int nw   = gridDim.x << 2;
    bool v4l = lane < (HDIM - 256);   // slot 4 covers cols 256..299 (lane<44)

    // resident packed We columns + be + res (one-time, ~50 VGPRs)
    h2v Wr[5][8];
    float bev[5], rev[5];
#pragma unroll
    for (int i = 0; i < 5; i++){
        bool ok = (i < 4) || v4l;
        int cc = ok ? (lane + 64*i) : lane;   // safe addr for masked lanes
        bev[i] = ok ? be[cc] : 0.f;
        rev[i] = ok ? res[cc] : 0.f;
        const uint4* wp = (const uint4*)(Weh + (size_t)cc*8);
        uint4 wa = wp[0], wb = wp[1];
        Wr[i][0] = u2h(wa.x); Wr[i][1] = u2h(wa.y); Wr[i][2] = u2h(wa.z); Wr[i][3] = u2h(wa.w);
        Wr[i][4] = u2h(wb.x); Wr[i][5] = u2h(wb.y); Wr[i][6] = u2h(wb.z); Wr[i][7] = u2h(wb.w);
    }

    for (int d = wid; d < N; d += nw){
        float id = invd[d];
        const _Float16* hrow = hp + (size_t)d*HDIM;
        float acc[5];
#pragma unroll
        for (int i = 0; i < 5; i++){
            bool ok = (i < 4) || v4l;
            int cc = ok ? (lane + 64*i) : lane;
            acc[i] = ok ? fmaxf((float)hrow[cc] + rev[i], 0.f)*id : 0.f;
        }
        int e0 = off[d], e1 = off[d+1];
        int p = e0;
        for (; p + 2 <= e1; p += 2){
            int2 x0 = eaux[p], x1 = eaux[p+1];
            float n0 = __int_as_float(x0.y);
            float n1 = __int_as_float(x1.y);
            const _Float16* h0 = hp + (size_t)x0.x*HDIM;
            const _Float16* h1 = hp + (size_t)x1.x*HDIM;
            float av[5], bv[5];
#pragma unroll
            for (int i = 0; i < 5; i++){
                bool ok = (i < 4) || v4l;
                int cc = ok ? (lane + 64*i) : lane;
                av[i] = (float)h0[cc];
                bv[i] = (float)h1[cc];
            }
            const uint4* q = (const uint4*)(efph + (size_t)p*8);
            uint4 ea = q[0], eb = q[1], ec = q[2], ed = q[3];
            unsigned int e0u[8] = {ea.x,ea.y,ea.z,ea.w, eb.x,eb.y,eb.z,eb.w};
            unsigned int e1u[8] = {ec.x,ec.y,ec.z,ec.w, ed.x,ed.y,ed.z,ed.w};
            float m[5];
#pragma unroll
            for (int i = 0; i < 5; i++) m[i] = bev[i];
#pragma unroll
            for (int k = 0; k < 8; k++){
                h2v e2 = u2h(e0u[k]);
#pragma unroll
                for (int i = 0; i < 5; i++) m[i] = dot2f(e2, Wr[i][k], m[i]);
            }
#pragma unroll
            for (int i = 0; i < 5; i++) acc[i] += fmaxf(av[i] + m[i], 0.f)*n0;
#pragma unroll
            for (int i = 0; i < 5; i++) m[i] = bev[i];
#pragma unroll
            for (int k = 0; k < 8; k++){
                h2v e2 = u2h(e1u[k]);
#pragma unroll
                for (int i = 0; i < 5; i++) m[i] = dot2f(e2, Wr[i][k], m[i]);
            }
#pragma unroll
            for (int i = 0; i < 5; i++) acc[i] += fmaxf(bv[i] + m[i], 0.f)*n1;
        }
        if (p < e1){
            int2 x0 = eaux[p];
            float n0 = __int_as_float(x0.y);
            const _Float16* h0 = hp + (size_t)x0.x*HDIM;
            float av[5];
#pragma unroll
            for (int i = 0; i < 5; i++){
                bool ok = (i < 4) || v4l;
                int cc = ok ? (lane + 64*i) : lane;
                av[i] = (float)h0[cc];
            }
            const uint4* q = (const uint4*)(efph + (size_t)p*8);
            uint4 ea = q[0], eb = q[1];
            unsigned int e0u[8] = {ea.x,ea.y,ea.z,ea.w, eb.x,eb.y,eb.z,eb.w};
            float m[5];
#pragma unroll
            for (int i = 0; i < 5; i++) m[i] = bev[i];
#pragma unroll
            for (int k = 0; k < 8; k++){
                h2v e2 = u2h(e0u[k]);
#pragma unroll
                for (int i = 0; i < 5; i++) m[i] = dot2f(e2, Wr[i][k], m[i]);
            }
#pragma unroll
            for (int i = 0; i < 5; i++) acc[i] += fmaxf(av[i] + m[i], 0.f)*n0;
        }
        if (useH){
            _Float16* orow = outh + (size_t)d*HDIM;
#pragma unroll
            for (int i = 0; i < 5; i++){
                if ((i < 4) || v4l)
                    __builtin_nontemporal_store((_Float16)acc[i], &orow[lane + 64*i]);
            }
        } else {
            float* orow = outf + (size_t)d*HDIM;
#pragma unroll
            for (int i = 0; i < 5; i++){
                if ((i < 4) || v4l)
                    __builtin_nontemporal_store(acc[i], &orow[lane + 64*i]);
            }
        }
    }
}

// ---------------- batchnorm: column stats (f64, 4 chains), f32 + fp16 variants ----------------
__global__ void k_colstats(const float* __restrict__ x, int rows, int cols, int rpb,
                           double* __restrict__ stats){
    int c = blockIdx.y*blockDim.x + threadIdx.x;
    if (c >= cols) return;
    int r0 = blockIdx.x * rpb;
    int r1 = min(rows, r0 + rpb);
    double s0 = 0.0, s1 = 0.0, s2 = 0.0, s3 = 0.0;
    double q0 = 0.0, q1 = 0.0, q2 = 0.0, q3 = 0.0;
    int r = r0;
    for (; r + 4 <= r1; r += 4){
        float va = x[(size_t)r*cols + c];
        float vb = x[(size_t)(r+1)*cols + c];
        float vc = x[(size_t)(r+2)*cols + c];
        float vd = x[(size_t)(r+3)*cols + c];
        s0 += va; q0 += (double)va*va;
        s1 += vb; q1 += (double)vb*vb;
        s2 += vc; q2 += (double)vc*vc;
        s3 += vd; q3 += (double)vd*vd;
    }
    for (; r < r1; ++r){
        float v = x[(size_t)r*cols + c];
        s0 += v; q0 += (double)v*v;
    }
    unsafeAtomicAdd(&stats[c], (s0 + s1) + (s2 + s3));
    unsafeAtomicAdd(&stats[cols + c], (q0 + q1) + (q2 + q3));
}
__global__ void k_colstats_h(const _Float16* __restrict__ x, int rows, int cols, int rpb,
                             double* __restrict__ stats){
    int c = blockIdx.y*blockDim.x + threadIdx.x;
    if (c >= cols) return;
    int r0 = blockIdx.x * rpb;
    int r1 = min(rows, r0 + rpb);
    double s0 = 0.0, s1 = 0.0, s2 = 0.0, s3 = 0.0;
    double q0 = 0.0, q1 = 0.0, q2 = 0.0, q3 = 0.0;
    int r = r0;
    for (; r + 4 <= r1; r += 4){
        float va = (float)x[(size_t)r*cols + c];
        float vb = (float)x[(size_t)(r+1)*cols + c];
        float vc = (float)x[(size_t)(r+2)*cols + c];
        float vd = (float)x[(size_t)(r+3)*cols + c];
        s0 += va; q0 += (double)va*va;
        s1 += vb; q1 += (double)vb*vb;
        s2 += vc; q2 += (double)vc*vc;
        s3 += vd; q3 += (double)vd*vd;
    }
    for (; r < r1; ++r){
        float v = (float)x[(size_t)r*cols + c];
        s0 += v; q0 += (double)v*v;
    }
    unsafeAtomicAdd(&stats[c], (s0 + s1) + (s2 + s3));
    unsafeAtomicAdd(&stats[cols + c], (q0 + q1) + (q2 + q3));
}
__global__ void k_bn_finalize(const double* __restrict__ stats, const float* __restrict__ g,
                              const float* __restrict__ b, int cols, float rowsf, float* __restrict__ ss){
    int c = blockIdx.x*blockDim.x + threadIdx.x;
    if (c < cols){
        float mean = (float)(stats[c] / rowsf);
        float var  = (float)(stats[cols + c] / rowsf) - mean*mean;
        var = fmaxf(var, 0.f);
        float sc = g[c] * rsqrtf(var + BNEPS);
        ss[c] = sc;
        ss[cols + c] = b[c] - mean*sc;
    }
}
template<int COLS>
__global__ void k_bn_apply(float* __restrict__ x, const float* __restrict__ ss, int total, int relu){
    int t = blockIdx.x*blockDim.x + threadIdx.x;
    if (t < total){
        int c = t % COLS;
        float v = x[t]*ss[c] + ss[COLS + c];
        if (relu) v = fmaxf(v, 0.f);
        x[t] = v;
    }
}
// BN+relu applied to x (COLS cols) and written as padded fp16 (KPAD cols); x unchanged
template<int COLS, int KPAD>
__global__ void k_bn_applyh(const float* __restrict__ x, const float* __restrict__ ss,
                            _Float16* __restrict__ xh, int rows){
    int t = blockIdx.x*blockDim.x + threadIdx.x;
    if (t >= rows*KPAD) return;
    int i = t / KPAD, c = t - i*KPAD;
    if (c < COLS){
        float v = x[(size_t)i*COLS + c]*ss[c] + ss[COLS + c];
        xh[t] = (_Float16)fmaxf(v, 0.f);
    } else xh[t] = (_Float16)0.f;
}

extern "C" void kernel_launch(void* const* d_in, const int* in_sizes, int n_in,
                              void* d_out, int out_size, void* d_ws, size_t ws_size,
                              hipStream_t stream){
    const int*   node_types = (const int*)d_in[0];
    const float* edge_feats = (const float*)d_in[1];
    const int*   src        = (const int*)d_in[2];
    const int*   dst        = (const int*)d_in[3];
    const int*   gid        = (const int*)d_in[4];
    const float* node_emb   = (const float*)d_in[6];
    const float* Wn         = (const float*)d_in[7];
    const float* bn_lin     = (const float*)d_in[8];
    const float* We         = (const float*)d_in[9];
    const float* be         = (const float*)d_in[10];
    const float* res_emb    = (const float*)d_in[11];
    const float* bn_gamma   = (const float*)d_in[12];
    const float* bn_beta    = (const float*)d_in[13];
    const float* vn_emb     = (const float*)d_in[14];
    const float* vW1        = (const float*)d_in[15];
    const float* vb1        = (const float*)d_in[16];
    const float* vg1        = (const float*)d_in[17];
    const float* vbt1       = (const float*)d_in[18];
    const float* vW2        = (const float*)d_in[19];
    const float* vb2        = (const float*)d_in[20];
    const float* vg2        = (const float*)d_in[21];
    const float* vbt2       = (const float*)d_in[22];

    const int N = in_sizes[0];
    const int E = in_sizes[2];
    const int B = BGR;
    float* out = (float*)d_out;          // final-layer agg result / final h

    char* w = (char*)d_ws;
    _Float16* hph  = (_Float16*)w; w += (size_t)N*HDIM*sizeof(_Float16);
    w = (char*)(((size_t)w + 31) & ~(size_t)31);
    _Float16* aggh = (_Float16*)w; w += (size_t)N*HDIM*sizeof(_Float16);
    w = (char*)(((size_t)w + 31) & ~(size_t)31);
    float*  degs  = (float*)w;  w += (size_t)N*sizeof(float);
    float*  invd  = (float*)w;  w += (size_t)N*sizeof(float);
    float*  vfeat = (float*)w;  w += (size_t)B*HDIM*sizeof(float);
    float*  vsum  = (float*)w;  w += (size_t)B*HDIM*sizeof(float);
    float*  zbuf  = (float*)w;  w += (size_t)B*2*HDIM*sizeof(float);
    double* stats = (double*)w; w += (size_t)2*2*HDIM*sizeof(double);
    float*  ssn   = (float*)w;  w += (size_t)2*HDIM*sizeof(float);
    float*  ssv   = (float*)w;  w += (size_t)2*2*HDIM*sizeof(float);
    int*    cnt   = (int*)w;    w += (size_t)N*sizeof(int);
    int*    coff  = (int*)w;    w += (size_t)(N+1)*sizeof(int);
    int*    fillc = (int*)w;    w += (size_t)N*sizeof(int);
    int*    eid   = (int*)w;    w += (size_t)E*sizeof(int);
    int*    part  = (int*)w;    w += (size_t)512*sizeof(int);
    int*    gstart= (int*)w;    w += (size_t)(B+1)*sizeof(int);
    w = (char*)(((size_t)w + 31) & ~(size_t)31);
    int2*   eaux  = (int2*)w;   w += (size_t)E*sizeof(int2);
    h2v*    efph  = (h2v*)w;    w += (size_t)E*8*sizeof(h2v);
    h2v*    Weh   = (h2v*)w;    w += (size_t)NL*HDIM*8*sizeof(h2v);
    unsigned short* Xb  = (unsigned short*)w; w += (size_t)N*KP1*sizeof(unsigned short);
    unsigned short* Wnb = (unsigned short*)w; w += (size_t)NL*HDIM*KP1*sizeof(unsigned short);
    _Float16* vsumh = (_Float16*)w; w += (size_t)B*KP1*sizeof(_Float16);
    _Float16* zbufh = (_Float16*)w; w += (size_t)B*KP2*sizeof(_Float16);
    _Float16* W1h   = (_Float16*)w; w += (size_t)(NL-1)*2*HDIM*KP1*sizeof(_Float16);
    _Float16* W2h   = (_Float16*)w; w += (size_t)(NL-1)*HDIM*KP2*sizeof(_Float16);

    const int NT = N*HDIM;
    const int BT = B*HDIM;
    auto cdiv = [](int a, int b){ return (a + b - 1)/b; };
    const int nb = cdiv(N, 256);

    // ---- setup: degrees + CSR + permuted edge data + graph ranges ----
    (void)hipMemsetAsync(cnt, 0, (size_t)N*sizeof(int), stream);
    k_count_deg<<<cdiv(E,256),256,0,stream>>>(dst, cnt, E);
    k_deg<<<nb,256,0,stream>>>(cnt, degs, invd, N);
    k_scan_partial<<<nb,256,0,stream>>>(cnt, part, N);
    k_scan_blocks<<<1,512,0,stream>>>(part, nb);
    k_scan_final<<<nb,256,0,stream>>>(cnt, part, coff, N);
    (void)hipMemsetAsync(fillc, 0, (size_t)N*sizeof(int), stream);
    k_fill<<<cdiv(E,256),256,0,stream>>>(dst, coff, fillc, eid, E);
    k_permute<<<cdiv(E,256),256,0,stream>>>(eid, src, dst, degs, edge_feats, eaux, efph, E);
    k_gstart<<<nb,256,0,stream>>>(gid, gstart, N, B);
    // ---- setup: weights, X0 (+ fused layer-0 segment sum) ----
    for (int l = 0; l < NL; l++)
        k_wt<<<cdiv(HDIM*KP1,256),256,0,stream>>>(Wn + (size_t)l*HDIM*HDIM,
                                                  Wnb + (size_t)l*HDIM*KP1, HDIM, HDIM, KP1);
    for (int l = 1; l < NL-1; l++){
        k_wt16<<<cdiv(2*HDIM*KP1,256),256,0,stream>>>(vW1 + (size_t)l*HDIM*2*HDIM,
                                                      W1h + (size_t)l*2*HDIM*KP1, HDIM, 2*HDIM, KP1);
        k_wt16<<<cdiv(HDIM*KP2,256),256,0,stream>>>(vW2 + (size_t)l*2*HDIM*HDIM,
                                                    W2h + (size_t)l*HDIM*KP2, 2*HDIM, HDIM, KP2);
    }
    k_wehalf<<<cdiv(NL*HDIM*8,256),256,0,stream>>>(We, Weh, NL*HDIM*8);
    // fused: Xb0 = bf16(emb[nt] + vn), vsum0 = segsum + vn
    k_x0seg<<<B,KP1,0,stream>>>(node_emb, node_types, vn_emb, gstart, Xb, vsum, vsumh);

    const int nbx = cdiv(HDIM,64);               // 5 col-tiles
    const int ngemm = nbx * cdiv(N,128);         // 1D grid, XCD-swizzled in-kernel
    for (int l = 0; l < NL; l++){
        // hp(fp16) = Xb @ Wn[l] + bn_lin[l]  (XCD-chunked swizzle for A-tile L2 reuse)
        k_gemm_mfma<<<ngemm,256,0,stream>>>(
            Xb, KP1, Wnb + (size_t)l*HDIM*KP1, KP1, bn_lin + (size_t)l*HDIM, hph, N, KP1, HDIM, nbx);
        int mid = (l < NL-1);
        // agg = residual + CSR-aggregated edge messages (fp16 intermediate for mid layers)
        k_agg<<<4096,256,0,stream>>>(hph, res_emb + (size_t)l*HDIM, invd,
                                     efph, eaux, coff,
                                     Weh + (size_t)l*HDIM*8, be + (size_t)l*HDIM,
                                     aggh, out, mid, N);
        // node BN stats (rpb=64 -> 1563 blocks; 4-chain ILP)
        (void)hipMemsetAsync(stats, 0, (size_t)2*HDIM*sizeof(double), stream);
        if (mid)
            k_colstats_h<<<dim3(cdiv(N,64),1),320,0,stream>>>(aggh, N, HDIM, 64, stats);
        else
            k_colstats<<<dim3(cdiv(N,64),1),320,0,stream>>>(out, N, HDIM, 64, stats);
        k_bn_finalize<<<1,320,0,stream>>>(stats, bn_gamma + (size_t)l*HDIM, bn_beta + (size_t)l*HDIM,
                                          HDIM, (float)N, ssn);
        if (l == 0){
            // ---- layer-0 vnode MLP: FULL f32 (rank-1 vsum -> BN sign-sensitivity) ----
            k_gemm<<<dim3(cdiv(B,64), cdiv(2*HDIM,64)),256,0,stream>>>(
                vsum, vW1, vb1, zbuf, B, HDIM, 2*HDIM);
            (void)hipMemsetAsync(stats, 0, (size_t)2*2*HDIM*sizeof(double), stream);
            k_colstats<<<dim3(cdiv(B,32),2),320,0,stream>>>(zbuf, B, 2*HDIM, 32, stats);
            k_bn_finalize<<<1,640,0,stream>>>(stats, vg1, vbt1, 2*HDIM, (float)B, ssv);
            k_bn_apply<2*HDIM><<<cdiv(B*2*HDIM,256),256,0,stream>>>(zbuf, ssv, B*2*HDIM, 1);
            k_gemm<<<dim3(cdiv(B,64), cdiv(HDIM,64)),256,0,stream>>>(
                zbuf, vW2, vb2, vfeat, B, 2*HDIM, HDIM);
            (void)hipMemsetAsync(stats, 0, (size_t)2*HDIM*sizeof(double), stream);
            k_colstats<<<dim3(cdiv(B,32),1),320,0,stream>>>(vfeat, B, HDIM, 32, stats);
            k_bn_finalize<<<1,320,0,stream>>>(stats, vg2, vbt2, HDIM, (float)B, ssv);
            k_bn_apply<HDIM><<<cdiv(BT,256),256,0,stream>>>(vfeat, ssv, BT, 1);
            k_bnvseg<<<B,KP1,0,stream>>>(aggh, ssn, vfeat, gstart, Xb, vsumh, 1);
        } else if (l < NL-1){
            // ---- layers 1..3 vnode MLP: fp16 MFMA (full-rank vsum, concentration-safe) ----
            k_gemm_mfma_h<<<dim3(cdiv(B,128), cdiv(2*HDIM,64)),256,0,stream>>>(
                vsumh, KP1, W1h + (size_t)l*2*HDIM*KP1, KP1, vb1 + (size_t)l*2*HDIM,
                zbuf, B, KP1, 2*HDIM);
            (void)hipMemsetAsync(stats, 0, (size_t)2*2*HDIM*sizeof(double), stream);
            k_colstats<<<dim3(cdiv(B,32),2),320,0,stream>>>(zbuf, B, 2*HDIM, 32, stats);
            k_bn_finalize<<<1,640,0,stream>>>(stats, vg1 + (size_t)l*2*HDIM, vbt1 + (size_t)l*2*HDIM,
                                              2*HDIM, (float)B, ssv);
            k_bn_applyh<2*HDIM, KP2><<<cdiv(B*KP2,256),256,0,stream>>>(zbuf, ssv, zbufh, B);
            k_gemm_mfma_h<<<dim3(cdiv(B,128), cdiv(HDIM,64)),256,0,stream>>>(
                zbufh, KP2, W2h + (size_t)l*HDIM*KP2, KP2, vb2 + (size_t)l*HDIM,
                vfeat, B, KP2, HDIM);
            (void)hipMemsetAsync(stats, 0, (size_t)2*HDIM*sizeof(double), stream);
            k_colstats<<<dim3(cdiv(B,32),1),320,0,stream>>>(vfeat, B, HDIM, 32, stats);
            k_bn_finalize<<<1,320,0,stream>>>(stats, vg2 + (size_t)l*HDIM, vbt2 + (size_t)l*HDIM,
                                              HDIM, (float)B, ssv);
            k_bn_apply<HDIM><<<cdiv(BT,256),256,0,stream>>>(vfeat, ssv, BT, 1);
            k_bnvseg<<<B,KP1,0,stream>>>(aggh, ssn, vfeat, gstart, Xb, vsumh,
                                         (l < NL-2) ? 1 : 0);
        } else {
            k_bn_apply<HDIM><<<cdiv(NT,256),256,0,stream>>>(out, ssn, NT, 0);
        }
    }
}

// Round 19
// 1797.971 us; speedup vs baseline: 2.0483x; 2.0483x over previous
//
#include <hip/hip_runtime.h>
#include <hip/hip_bf16.h>

#define HDIM 300
#define FEAT 16
#define NL 5
#define BGR 4096
#define BNEPS 1e-5f
#define KP1 320   // K=300 padded to multiple of 32
#define KP2 640   // K=600 padded to multiple of 32

typedef __attribute__((ext_vector_type(8))) short s8v;
typedef __attribute__((ext_vector_type(4))) float f4v;
typedef __attribute__((ext_vector_type(2))) _Float16 h2v;
typedef __attribute__((ext_vector_type(8))) _Float16 h8v;

__device__ __forceinline__ unsigned short f2bu(float f){
    __hip_bfloat16 h = __float2bfloat16(f);
    return __builtin_bit_cast(unsigned short, h);
}
__device__ __forceinline__ h2v u2h(unsigned int u){
    return __builtin_bit_cast(h2v, u);
}
// fp16-pair dot with f32 accumulate: one v_dot2_f32_f16 instead of two fma_mix
__device__ __forceinline__ float dot2f(h2v a, h2v b, float c){
#if __has_builtin(__builtin_amdgcn_fdot2)
    return __builtin_amdgcn_fdot2(a, b, c, false);
#else
    return fmaf((float)a.x, (float)b.x, fmaf((float)a.y, (float)b.y, c));
#endif
}

// ---------------- setup kernels ----------------
__global__ void k_count_deg(const int* __restrict__ dst, int* __restrict__ cnt, int E){
    int e = blockIdx.x*blockDim.x + threadIdx.x;
    if (e < E) atomicAdd(&cnt[dst[e]], 1);
}
__global__ void k_deg(const int* __restrict__ cnt, float* __restrict__ degs,
                      float* __restrict__ invd, int N){
    int i = blockIdx.x*blockDim.x + threadIdx.x;
    if (i < N){
        float d = (float)cnt[i] + 1.0f;
        degs[i] = d;
        invd[i] = 1.0f / d;
    }
}
// --- exclusive scan of cnt -> off (off[N]=E), 3 phases ---
__global__ void k_scan_partial(const int* __restrict__ cnt, int* __restrict__ part, int N){
    __shared__ int sm[256];
    int i = blockIdx.x*256 + threadIdx.x;
    sm[threadIdx.x] = (i < N) ? cnt[i] : 0;
    __syncthreads();
    for (int s = 128; s > 0; s >>= 1){
        if (threadIdx.x < s) sm[threadIdx.x] += sm[threadIdx.x + s];
        __syncthreads();
    }
    if (threadIdx.x == 0) part[blockIdx.x] = sm[0];
}
__global__ void k_scan_blocks(int* __restrict__ part, int nb){
    __shared__ int sm[512];
    int t = threadIdx.x;
    int v = (t < nb) ? part[t] : 0;
    sm[t] = v; __syncthreads();
    for (int o = 1; o < 512; o <<= 1){
        int x = (t >= o) ? sm[t - o] : 0;
        __syncthreads();
        sm[t] += x;
        __syncthreads();
    }
    if (t < nb) part[t] = sm[t] - v;   // exclusive
}
__global__ void k_scan_final(const int* __restrict__ cnt, const int* __restrict__ part,
                             int* __restrict__ off, int N){
    __shared__ int sm[256];
    int i = blockIdx.x*256 + threadIdx.x;
    int v = (i < N) ? cnt[i] : 0;
    sm[threadIdx.x] = v; __syncthreads();
    for (int o = 1; o < 256; o <<= 1){
        int x = (threadIdx.x >= o) ? sm[threadIdx.x - o] : 0;
        __syncthreads();
        sm[threadIdx.x] += x;
        __syncthreads();
    }
    if (i < N){
        off[i] = part[blockIdx.x] + sm[threadIdx.x] - v;
        if (i == N-1) off[N] = part[blockIdx.x] + sm[threadIdx.x];
    }
}
__global__ void k_fill(const int* __restrict__ dst, const int* __restrict__ off,
                       int* __restrict__ fillc, int* __restrict__ eid, int E){
    int e = blockIdx.x*blockDim.x + threadIdx.x;
    if (e < E){
        int d = dst[e];
        int p = off[d] + atomicAdd(&fillc[d], 1);
        eid[p] = e;
    }
}
// permute edge data into CSR (dst-grouped) order:
//   eaux[p] = {src, rsqrt(deg[src]*deg[dst]) as bits}
//   efph[p][k] = fp16(edge_feats[e][k])  (32B per edge)
__global__ void k_permute(const int* __restrict__ eid, const int* __restrict__ src,
                          const int* __restrict__ dst, const float* __restrict__ degs,
                          const float* __restrict__ ef,
                          int2* __restrict__ eaux, h2v* __restrict__ efph, int E){
    int p = blockIdx.x*blockDim.x + threadIdx.x;
    if (p >= E) return;
    int e = eid[p];
    int s = src[e];
    float n = rsqrtf(degs[s]*degs[dst[e]]);
    eaux[p] = make_int2(s, __float_as_int(n));
    const float4* s4 = (const float4*)(ef + (size_t)e*FEAT);
    float4 A = s4[0], B = s4[1], C = s4[2], D = s4[3];
    h2v* op = efph + (size_t)p*8;
    op[0] = (h2v){(_Float16)A.x, (_Float16)A.y};
    op[1] = (h2v){(_Float16)A.z, (_Float16)A.w};
    op[2] = (h2v){(_Float16)B.x, (_Float16)B.y};
    op[3] = (h2v){(_Float16)B.z, (_Float16)B.w};
    op[4] = (h2v){(_Float16)C.x, (_Float16)C.y};
    op[5] = (h2v){(_Float16)C.z, (_Float16)C.w};
    op[6] = (h2v){(_Float16)D.x, (_Float16)D.y};
    op[7] = (h2v){(_Float16)D.z, (_Float16)D.w};
}
// pack We (all layers) to fp16 pairs: Weh[(l*HDIM + c)*8 + kk] = {We[l][2kk][c], We[l][2kk+1][c]}
__global__ void k_wehalf(const float* __restrict__ We, h2v* __restrict__ Weh, int total){
    int t = blockIdx.x*blockDim.x + threadIdx.x;
    if (t >= total) return;
    int kk = t & 7;
    int lc = t >> 3;
    int c = lc % HDIM;
    int l = lc / HDIM;
    const float* w = We + (size_t)l*FEAT*HDIM;
    Weh[t] = (h2v){(_Float16)w[(size_t)(2*kk)*HDIM + c], (_Float16)w[(size_t)(2*kk+1)*HDIM + c]};
}
// gid is sorted: gstart[g] = first node index with gid >= g ; gstart[B] = N
__global__ void k_gstart(const int* __restrict__ gid, int* __restrict__ gstart, int N, int B){
    int i = blockIdx.x*blockDim.x + threadIdx.x;
    if (i >= N) return;
    int prev = (i == 0) ? -1 : gid[i-1];
    int cur = gid[i];
    for (int g = prev + 1; g <= cur; g++) gstart[g] = i;
    if (i == N-1) for (int g = cur + 1; g <= B; g++) gstart[g] = N;
}
// weight transpose+pad to bf16: Wt[n][kp] = W[k][n]  (W is K x Ncol row-major)
__global__ void k_wt(const float* __restrict__ W, unsigned short* __restrict__ Wt,
                     int K, int Ncol, int Kpad){
    int t = blockIdx.x*blockDim.x + threadIdx.x;
    if (t >= Ncol*Kpad) return;
    int n = t / Kpad, kp = t - n*Kpad;
    Wt[t] = (kp < K) ? f2bu(W[(size_t)kp*Ncol + n]) : (unsigned short)0;
}
// weight transpose+pad to fp16 (vnode layers>=1: needs 11-bit mantissa, bf16 fails tolerance)
__global__ void k_wt16(const float* __restrict__ W, _Float16* __restrict__ Wt,
                       int K, int Ncol, int Kpad){
    int t = blockIdx.x*blockDim.x + threadIdx.x;
    if (t >= Ncol*Kpad) return;
    int n = t / Kpad, kp = t - n*Kpad;
    Wt[t] = (kp < K) ? (_Float16)W[(size_t)kp*Ncol + n] : (_Float16)0.f;
}

// ---------------- FUSED layer-0 X build + segment sum (per-graph blocks) ----------------
__global__ void k_x0seg(const float* __restrict__ emb, const int* __restrict__ nt,
                        const float* __restrict__ vn, const int* __restrict__ gstart,
                        unsigned short* __restrict__ Xb,
                        float* __restrict__ vsum, _Float16* __restrict__ vsumh){
    int g = blockIdx.x;
    int c = threadIdx.x;
    if (c >= KP1) return;
    int r0 = gstart[g], r1 = gstart[g+1];
    if (c >= HDIM){
        for (int r = r0; r < r1; ++r) Xb[(size_t)r*KP1 + c] = 0;
        vsumh[(size_t)g*KP1 + c] = (_Float16)0.f;
        return;
    }
    float vf = vn[c];
    float s = 0.f;
    for (int r = r0; r < r1; ++r){
        float v = emb[(size_t)nt[r]*HDIM + c] + vf;
        Xb[(size_t)r*KP1 + c] = f2bu(v);
        s += v;
    }
    float t = s + vf;
    vsum[(size_t)g*HDIM + c] = t;
    vsumh[(size_t)g*KP1 + c] = (_Float16)t;
}

// ---------------- FUSED mid-layer BN+vfeat + segment sum (fp16 agg input) ----------------
__global__ void k_bnvseg(const _Float16* __restrict__ agg, const float* __restrict__ ss,
                         const float* __restrict__ vfeat, const int* __restrict__ gstart,
                         unsigned short* __restrict__ Xb,
                         _Float16* __restrict__ vsumh, int writeV){
    int g = blockIdx.x;
    int c = threadIdx.x;
    if (c >= KP1) return;
    int r0 = gstart[g], r1 = gstart[g+1];
    if (c >= HDIM){
        for (int r = r0; r < r1; ++r) Xb[(size_t)r*KP1 + c] = 0;
        if (writeV) vsumh[(size_t)g*KP1 + c] = (_Float16)0.f;
        return;
    }
    float sc = ss[c], sb = ss[HDIM + c];
    float vf = vfeat[(size_t)g*HDIM + c];
    float s = 0.f;
    for (int r = r0; r < r1; ++r){
        float v = fmaxf((float)agg[(size_t)r*HDIM + c]*sc + sb, 0.f) + vf;
        Xb[(size_t)r*KP1 + c] = f2bu(v);
        s += v;
    }
    if (writeV) vsumh[(size_t)g*KP1 + c] = (_Float16)(s + vf);
}

// ---------------- MFMA bf16 GEMM v4 (main path -> fp16 hp) ----------------
// 1D grid + bijective XCD-chunked swizzle (m204): all 5 col-tiles of a row-tile
// on the SAME XCD L2 -> A-tile fetched once. (Round-15: confirmed win.)
__global__ __launch_bounds__(256) void k_gemm_mfma(
    const unsigned short* __restrict__ A, int lda,
    const unsigned short* __restrict__ Wt, int ldw,
    const float* __restrict__ bias,
    _Float16* __restrict__ C, int M, int Kpad, int Ncol, int nbx)
{
    __shared__ short As[2][128][44];
    __shared__ short Bs[2][64][44];
    int tid = threadIdx.x;
    int nwg = gridDim.x;
    int q = nwg >> 3, r = nwg & 7;
    int orig = blockIdx.x;
    int xcd = orig & 7;
    int idx = orig >> 3;
    int lid = (xcd < r ? xcd*(q+1) : r*(q+1) + (xcd - r)*q) + idx;
    int bm = (lid / nbx) * 128;
    int bn = (lid % nbx) * 64;
    int lane = tid & 63;
    int w = tid >> 6;
    int wm = w & 1, wn = w >> 1;
    int l15 = lane & 15, l4 = lane >> 4;
    f4v acc[4][2];
#pragma unroll
    for (int mi = 0; mi < 4; mi++)
#pragma unroll
        for (int ni = 0; ni < 2; ni++) acc[mi][ni] = (f4v){0.f,0.f,0.f,0.f};

    int arow = tid >> 1;
    int akc  = (tid & 1) * 2;
    int gmA  = bm + arow;
    int brow = tid >> 2;
    int bkc  = tid & 3;
    int gnB  = bn + brow;
    const s8v zv = (s8v){0,0,0,0,0,0,0,0};
    int nT = Kpad / 32;

    auto loadT = [&](int k0, s8v& a0, s8v& a1, s8v& b0){
        a0 = zv; a1 = zv; b0 = zv;
        if (gmA < M){
            const s8v* ap = (const s8v*)(A + (size_t)gmA*lda + k0 + akc*8);
            a0 = ap[0]; a1 = ap[1];
        }
        if (gnB < Ncol) b0 = *(const s8v*)(Wt + (size_t)gnB*ldw + k0 + bkc*8);
    };
    auto storeT = [&](int buf, s8v a0, s8v a1, s8v b0){
        *(s8v*)&As[buf][arow][akc*8]     = a0;
        *(s8v*)&As[buf][arow][akc*8 + 8] = a1;
        *(s8v*)&Bs[buf][brow][bkc*8] = b0;
    };

    s8v a0, a1, b0;
    loadT(0, a0, a1, b0);
    storeT(0, a0, a1, b0);
    __syncthreads();

    int cur = 0;
    for (int t = 0; t < nT; ++t){
        if (t + 1 < nT) loadT((t+1)*32, a0, a1, b0);
        s8v af[4], bf[2];
#pragma unroll
        for (int mi = 0; mi < 4; mi++) af[mi] = *(const s8v*)&As[cur][wm*64 + mi*16 + l15][l4*8];
#pragma unroll
        for (int ni = 0; ni < 2; ni++) bf[ni] = *(const s8v*)&Bs[cur][wn*32 + ni*16 + l15][l4*8];
#pragma unroll
        for (int mi = 0; mi < 4; mi++)
#pragma unroll
            for (int ni = 0; ni < 2; ni++)
                acc[mi][ni] = __builtin_amdgcn_mfma_f32_16x16x32_bf16(af[mi], bf[ni], acc[mi][ni], 0, 0, 0);
        if (t + 1 < nT) storeT(cur ^ 1, a0, a1, b0);
        __syncthreads();
        cur ^= 1;
    }

#pragma unroll
    for (int ni = 0; ni < 2; ni++){
        int col = bn + wn*32 + ni*16 + l15;
        if (col >= Ncol) continue;
        float bia = bias[col];
#pragma unroll
        for (int mi = 0; mi < 4; mi++){
#pragma unroll
            for (int r2 = 0; r2 < 4; r2++){
                int row = bm + wm*64 + mi*16 + l4*4 + r2;
                if (row < M) C[(size_t)row*Ncol + col] = (_Float16)(acc[mi][ni][r2] + bia);
            }
        }
    }
}

// ---------------- MFMA fp16 GEMM (vnode layers>=1): C = A@Wt^T + bias ----------------
__global__ __launch_bounds__(256) void k_gemm_mfma_h(
    const _Float16* __restrict__ A, int lda,
    const _Float16* __restrict__ Wt, int ldw,
    const float* __restrict__ bias,
    float* __restrict__ C, int M, int Kpad, int Ncol)
{
    __shared__ _Float16 As[128][44];
    __shared__ _Float16 Bs[64][44];
    int tid = threadIdx.x;
    int bm = blockIdx.x * 128;
    int bn = blockIdx.y * 64;
    int lane = tid & 63;
    int w = tid >> 6;
    int wm = w & 1, wn = w >> 1;
    int l15 = lane & 15, l4 = lane >> 4;
    f4v acc[4][2];
#pragma unroll
    for (int mi = 0; mi < 4; mi++)
#pragma unroll
        for (int ni = 0; ni < 2; ni++) acc[mi][ni] = (f4v){0.f,0.f,0.f,0.f};

    int arow = tid >> 1;
    int akc  = (tid & 1) * 2;
    int gmA  = bm + arow;
    int brow = tid >> 2;
    int bkc  = tid & 3;
    int gnB  = bn + brow;
    const h8v zv = (h8v){0,0,0,0,0,0,0,0};

    for (int k0 = 0; k0 < Kpad; k0 += 32){
        __syncthreads();
        h8v a0 = zv, a1 = zv;
        if (gmA < M){
            const h8v* ap = (const h8v*)(A + (size_t)gmA*lda + k0 + akc*8);
            a0 = ap[0]; a1 = ap[1];
        }
        *(h8v*)&As[arow][akc*8]     = a0;
        *(h8v*)&As[arow][akc*8 + 8] = a1;
        h8v b0 = zv;
        if (gnB < Ncol) b0 = *(const h8v*)(Wt + (size_t)gnB*ldw + k0 + bkc*8);
        *(h8v*)&Bs[brow][bkc*8] = b0;
        __syncthreads();

        h8v af[4], bf[2];
#pragma unroll
        for (int mi = 0; mi < 4; mi++) af[mi] = *(const h8v*)&As[wm*64 + mi*16 + l15][l4*8];
#pragma unroll
        for (int ni = 0; ni < 2; ni++) bf[ni] = *(const h8v*)&Bs[wn*32 + ni*16 + l15][l4*8];
#pragma unroll
        for (int mi = 0; mi < 4; mi++)
#pragma unroll
            for (int ni = 0; ni < 2; ni++)
                acc[mi][ni] = __builtin_amdgcn_mfma_f32_16x16x32_f16(af[mi], bf[ni], acc[mi][ni], 0, 0, 0);
    }

#pragma unroll
    for (int ni = 0; ni < 2; ni++){
        int col = bn + wn*32 + ni*16 + l15;
        if (col >= Ncol) continue;
        float bia = bias[col];
#pragma unroll
        for (int mi = 0; mi < 4; mi++){
#pragma unroll
            for (int r = 0; r < 4; r++){
                int row = bm + wm*64 + mi*16 + l4*4 + r;
                if (row < M) C[(size_t)row*Ncol + col] = acc[mi][ni][r] + bia;
            }
        }
    }
}

// ---------------- f32 VALU GEMM v2 (layer-0 vnode path ONLY: precision-critical) ----------------
__global__ __launch_bounds__(256) void k_gemm(const float* __restrict__ A, const float* __restrict__ W,
                                              const float* __restrict__ bias, float* __restrict__ C,
                                              int M, int K, int Ncol){
    __shared__ float As[2][16][68];
    __shared__ float Ws[2][16][68];
    int tid = threadIdx.x;
    int bm = blockIdx.x * 64;
    int bn = blockIdx.y * 64;
    int tx = tid & 15;          // col group (4 cols)
    int ty = tid >> 4;          // row group (4 rows)
    float acc[4][4];
#pragma unroll
    for (int i = 0; i < 4; i++)
#pragma unroll
        for (int j = 0; j < 4; j++) acc[i][j] = 0.f;

    int ka  = tid & 15;
    int ra0 = tid >> 4;
    int colw = tid & 63;
    int kw0  = tid >> 6;
    int nT = (K + 15) / 16;

    auto loadA = [&](int k0, float av[4]){
#pragma unroll
        for (int j = 0; j < 4; j++){
            int gm = bm + ra0 + j*16, gk = k0 + ka;
            av[j] = (gm < M && gk < K) ? A[(size_t)gm*K + gk] : 0.f;
        }
    };
    auto loadW = [&](int k0, float wv[4]){
#pragma unroll
        for (int j = 0; j < 4; j++){
            int gk = k0 + kw0 + j*4, gn = bn + colw;
            wv[j] = (gk < K && gn < Ncol) ? W[(size_t)gk*Ncol + gn] : 0.f;
        }
    };
    auto storeT = [&](int buf, const float av[4], const float wv[4]){
#pragma unroll
        for (int j = 0; j < 4; j++) As[buf][ka][ra0 + j*16] = av[j];
#pragma unroll
        for (int j = 0; j < 4; j++) Ws[buf][kw0 + j*4][colw] = wv[j];
    };

    float av[4], wv[4];
    loadA(0, av); loadW(0, wv);
    storeT(0, av, wv);
    __syncthreads();

    int cur = 0;
    for (int t = 0; t < nT; ++t){
        if (t + 1 < nT){ loadA((t+1)*16, av); loadW((t+1)*16, wv); }
#pragma unroll
        for (int kk = 0; kk < 16; kk++){
            float a[4], b[4];
#pragma unroll
            for (int i = 0; i < 4; i++) a[i] = As[cur][kk][ty*4 + i];
#pragma unroll
            for (int j = 0; j < 4; j++) b[j] = Ws[cur][kk][tx*4 + j];
#pragma unroll
            for (int i = 0; i < 4; i++)
#pragma unroll
                for (int j = 0; j < 4; j++) acc[i][j] += a[i]*b[j];
        }
        if (t + 1 < nT) storeT(cur ^ 1, av, wv);
        __syncthreads();
        cur ^= 1;
    }

    float bb[4];
#pragma unroll
    for (int j = 0; j < 4; j++){ int gn = bn + tx*4 + j; bb[j] = (gn < Ncol) ? bias[gn] : 0.f; }
#pragma unroll
    for (int i = 0; i < 4; i++){
        int gm = bm + ty*4 + i;
        if (gm < M){
#pragma unroll
            for (int j = 0; j < 4; j++){
                int gn = bn + tx*4 + j;
                if (gn < Ncol) C[(size_t)gm*Ncol + gn] = acc[i][j] + bb[j];
            }
        }
    }
}

// ---------------- CSR aggregation v7 (REVERTED from v8) ----------------
// v8's (256,8) reproduced the round-1 spill: forced 64-VGPR budget -> Wr spilled
// to scratch (VGPR_Count 32, FETCH 1.1GB, 447us). VGPR_Count=60 under a 128
// budget does NOT imply fitting a 64 budget. (256,4) = 80.6us, no spill.
// out[d] = relu(hp[d]+res)*invd[d] + sum_p norm_p * relu(hp[src_p] + ef_p@We + be)
__global__ __launch_bounds__(256, 4) void k_agg(
    const _Float16* __restrict__ hp, const float* __restrict__ res,
    const float* __restrict__ invd,
    const h2v* __restrict__ efph, const int2* __restrict__ eaux,
    const int* __restrict__ off,
    const h2v* __restrict__ Weh, const float* __restrict__ be,
    _Float16* __restrict__ outh, float* __restrict__ outf, int useH, int N)
{
    int lane = threadIdx.x & 63;
    int wid  = blockIdx.x*4 + (threadIdx.x >> 6);
    int nw   = gridDim.x << 2;
    bool v4l = lane < (HDIM - 256);   // slot 4 covers cols 256..299 (lane<44)

    // resident packed We columns + be + res (one-time, ~50 VGPRs)
    h2v Wr[5][8];
    float bev[5], rev[5];
#pragma unroll
    for (int i = 0; i < 5; i++){
        bool ok = (i < 4) || v4l;
        int cc = ok ? (lane + 64*i) : lane;   // safe addr for masked lanes
        bev[i] = ok ? be[cc] : 0.f;
        rev[i] = ok ? res[cc] : 0.f;
        const uint4* wp = (const uint4*)(Weh + (size_t)cc*8);
        uint4 wa = wp[0], wb = wp[1];
        Wr[i][0] = u2h(wa.x); Wr[i][1] = u2h(wa.y); Wr[i][2] = u2h(wa.z); Wr[i][3] = u2h(wa.w);
        Wr[i][4] = u2h(wb.x); Wr[i][5] = u2h(wb.y); Wr[i][6] = u2h(wb.z); Wr[i][7] = u2h(wb.w);
    }

    for (int d = wid; d < N; d += nw){
        float id = invd[d];
        const _Float16* hrow = hp + (size_t)d*HDIM;
        float acc[5];
#pragma unroll
        for (int i = 0; i < 5; i++){
            bool ok = (i < 4) || v4l;
            int cc = ok ? (lane + 64*i) : lane;
            acc[i] = ok ? fmaxf((float)hrow[cc] + rev[i], 0.f)*id : 0.f;
        }
        int e0 = off[d], e1 = off[d+1];
        int p = e0;
        for (; p + 2 <= e1; p += 2){
            int2 x0 = eaux[p], x1 = eaux[p+1];
            float n0 = __int_as_float(x0.y);
            float n1 = __int_as_float(x1.y);
            const _Float16* h0 = hp + (size_t)x0.x*HDIM;
            const _Float16* h1 = hp + (size_t)x1.x*HDIM;
            float av[5], bv[5];
#pragma unroll
            for (int i = 0; i < 5; i++){
                bool ok = (i < 4) || v4l;
                int cc = ok ? (lane + 64*i) : lane;
                av[i] = (float)h0[cc];
                bv[i] = (float)h1[cc];
            }
            const uint4* q = (const uint4*)(efph + (size_t)p*8);
            uint4 ea = q[0], eb = q[1], ec = q[2], ed = q[3];
            unsigned int e0u[8] = {ea.x,ea.y,ea.z,ea.w, eb.x,eb.y,eb.z,eb.w};
            unsigned int e1u[8] = {ec.x,ec.y,ec.z,ec.w, ed.x,ed.y,ed.z,ed.w};
            float m[5];
#pragma unroll
            for (int i = 0; i < 5; i++) m[i] = bev[i];
#pragma unroll
            for (int k = 0; k < 8; k++){
                h2v e2 = u2h(e0u[k]);
#pragma unroll
                for (int i = 0; i < 5; i++) m[i] = dot2f(e2, Wr[i][k], m[i]);
            }
#pragma unroll
            for (int i = 0; i < 5; i++) acc[i] += fmaxf(av[i] + m[i], 0.f)*n0;
#pragma unroll
            for (int i = 0; i < 5; i++) m[i] = bev[i];
#pragma unroll
            for (int k = 0; k < 8; k++){
                h2v e2 = u2h(e1u[k]);
#pragma unroll
                for (int i = 0; i < 5; i++) m[i] = dot2f(e2, Wr[i][k], m[i]);
            }
#pragma unroll
            for (int i = 0; i < 5; i++) acc[i] += fmaxf(bv[i] + m[i], 0.f)*n1;
        }
        if (p < e1){
            int2 x0 = eaux[p];
            float n0 = __int_as_float(x0.y);
            const _Float16* h0 = hp + (size_t)x0.x*HDIM;
            float av[5];
#pragma unroll
            for (int i = 0; i < 5; i++){
                bool ok = (i < 4) || v4l;
                int cc = ok ? (lane + 64*i) : lane;
                av[i] = (float)h0[cc];
            }
            const uint4* q = (const uint4*)(efph + (size_t)p*8);
            uint4 ea = q[0], eb = q[1];
            unsigned int e0u[8] = {ea.x,ea.y,ea.z,ea.w, eb.x,eb.y,eb.z,eb.w};
            float m[5];
#pragma unroll
            for (int i = 0; i < 5; i++) m[i] = bev[i];
#pragma unroll
            for (int k = 0; k < 8; k++){
                h2v e2 = u2h(e0u[k]);
#pragma unroll
                for (int i = 0; i < 5; i++) m[i] = dot2f(e2, Wr[i][k], m[i]);
            }
#pragma unroll
            for (int i = 0; i < 5; i++) acc[i] += fmaxf(av[i] + m[i], 0.f)*n0;
        }
        if (useH){
            _Float16* orow = outh + (size_t)d*HDIM;
#pragma unroll
            for (int i = 0; i < 5; i++){
                if ((i < 4) || v4l)
                    __builtin_nontemporal_store((_Float16)acc[i], &orow[lane + 64*i]);
            }
        } else {
            float* orow = outf + (size_t)d*HDIM;
#pragma unroll
            for (int i = 0; i < 5; i++){
                if ((i < 4) || v4l)
                    __builtin_nontemporal_store(acc[i], &orow[lane + 64*i]);
            }
        }
    }
}

// ---------------- batchnorm: column stats (f64, 4 chains), f32 + fp16 variants ----------------
__global__ void k_colstats(const float* __restrict__ x, int rows, int cols, int rpb,
                           double* __restrict__ stats){
    int c = blockIdx.y*blockDim.x + threadIdx.x;
    if (c >= cols) return;
    int r0 = blockIdx.x * rpb;
    int r1 = min(rows, r0 + rpb);
    double s0 = 0.0, s1 = 0.0, s2 = 0.0, s3 = 0.0;
    double q0 = 0.0, q1 = 0.0, q2 = 0.0, q3 = 0.0;
    int r = r0;
    for (; r + 4 <= r1; r += 4){
        float va = x[(size_t)r*cols + c];
        float vb = x[(size_t)(r+1)*cols + c];
        float vc = x[(size_t)(r+2)*cols + c];
        float vd = x[(size_t)(r+3)*cols + c];
        s0 += va; q0 += (double)va*va;
        s1 += vb; q1 += (double)vb*vb;
        s2 += vc; q2 += (double)vc*vc;
        s3 += vd; q3 += (double)vd*vd;
    }
    for (; r < r1; ++r){
        float v = x[(size_t)r*cols + c];
        s0 += v; q0 += (double)v*v;
    }
    unsafeAtomicAdd(&stats[c], (s0 + s1) + (s2 + s3));
    unsafeAtomicAdd(&stats[cols + c], (q0 + q1) + (q2 + q3));
}
__global__ void k_colstats_h(const _Float16* __restrict__ x, int rows, int cols, int rpb,
                             double* __restrict__ stats){
    int c = blockIdx.y*blockDim.x + threadIdx.x;
    if (c >= cols) return;
    int r0 = blockIdx.x * rpb;
    int r1 = min(rows, r0 + rpb);
    double s0 = 0.0, s1 = 0.0, s2 = 0.0, s3 = 0.0;
    double q0 = 0.0, q1 = 0.0, q2 = 0.0, q3 = 0.0;
    int r = r0;
    for (; r + 4 <= r1; r += 4){
        float va = (float)x[(size_t)r*cols + c];
        float vb = (float)x[(size_t)(r+1)*cols + c];
        float vc = (float)x[(size_t)(r+2)*cols + c];
        float vd = (float)x[(size_t)(r+3)*cols + c];
        s0 += va; q0 += (double)va*va;
        s1 += vb; q1 += (double)vb*vb;
        s2 += vc; q2 += (double)vc*vc;
        s3 += vd; q3 += (double)vd*vd;
    }
    for (; r < r1; ++r){
        float v = (float)x[(size_t)r*cols + c];
        s0 += v; q0 += (double)v*v;
    }
    unsafeAtomicAdd(&stats[c], (s0 + s1) + (s2 + s3));
    unsafeAtomicAdd(&stats[cols + c], (q0 + q1) + (q2 + q3));
}
__global__ void k_bn_finalize(const double* __restrict__ stats, const float* __restrict__ g,
                              const float* __restrict__ b, int cols, float rowsf, float* __restrict__ ss){
    int c = blockIdx.x*blockDim.x + threadIdx.x;
    if (c < cols){
        float mean = (float)(stats[c] / rowsf);
        float var  = (float)(stats[cols + c] / rowsf) - mean*mean;
        var = fmaxf(var, 0.f);
        float sc = g[c] * rsqrtf(var + BNEPS);
        ss[c] = sc;
        ss[cols + c] = b[c] - mean*sc;
    }
}
template<int COLS>
__global__ void k_bn_apply(float* __restrict__ x, const float* __restrict__ ss, int total, int relu){
    int t = blockIdx.x*blockDim.x + threadIdx.x;
    if (t < total){
        int c = t % COLS;
        float v = x[t]*ss[c] + ss[COLS + c];
        if (relu) v = fmaxf(v, 0.f);
        x[t] = v;
    }
}
// BN+relu applied to x (COLS cols) and written as padded fp16 (KPAD cols); x unchanged
template<int COLS, int KPAD>
__global__ void k_bn_applyh(const float* __restrict__ x, const float* __restrict__ ss,
                            _Float16* __restrict__ xh, int rows){
    int t = blockIdx.x*blockDim.x + threadIdx.x;
    if (t >= rows*KPAD) return;
    int i = t / KPAD, c = t - i*KPAD;
    if (c < COLS){
        float v = x[(size_t)i*COLS + c]*ss[c] + ss[COLS + c];
        xh[t] = (_Float16)fmaxf(v, 0.f);
    } else xh[t] = (_Float16)0.f;
}

extern "C" void kernel_launch(void* const* d_in, const int* in_sizes, int n_in,
                              void* d_out, int out_size, void* d_ws, size_t ws_size,
                              hipStream_t stream){
    const int*   node_types = (const int*)d_in[0];
    const float* edge_feats = (const float*)d_in[1];
    const int*   src        = (const int*)d_in[2];
    const int*   dst        = (const int*)d_in[3];
    const int*   gid        = (const int*)d_in[4];
    const float* node_emb   = (const float*)d_in[6];
    const float* Wn         = (const float*)d_in[7];
    const float* bn_lin     = (const float*)d_in[8];
    const float* We         = (const float*)d_in[9];
    const float* be         = (const float*)d_in[10];
    const float* res_emb    = (const float*)d_in[11];
    const float* bn_gamma   = (const float*)d_in[12];
    const float* bn_beta    = (const float*)d_in[13];
    const float* vn_emb     = (const float*)d_in[14];
    const float* vW1        = (const float*)d_in[15];
    const float* vb1        = (const float*)d_in[16];
    const float* vg1        = (const float*)d_in[17];
    const float* vbt1       = (const float*)d_in[18];
    const float* vW2        = (const float*)d_in[19];
    const float* vb2        = (const float*)d_in[20];
    const float* vg2        = (const float*)d_in[21];
    const float* vbt2       = (const float*)d_in[22];

    const int N = in_sizes[0];
    const int E = in_sizes[2];
    const int B = BGR;
    float* out = (float*)d_out;          // final-layer agg result / final h

    char* w = (char*)d_ws;
    _Float16* hph  = (_Float16*)w; w += (size_t)N*HDIM*sizeof(_Float16);
    w = (char*)(((size_t)w + 31) & ~(size_t)31);
    _Float16* aggh = (_Float16*)w; w += (size_t)N*HDIM*sizeof(_Float16);
    w = (char*)(((size_t)w + 31) & ~(size_t)31);
    float*  degs  = (float*)w;  w += (size_t)N*sizeof(float);
    float*  invd  = (float*)w;  w += (size_t)N*sizeof(float);
    float*  vfeat = (float*)w;  w += (size_t)B*HDIM*sizeof(float);
    float*  vsum  = (float*)w;  w += (size_t)B*HDIM*sizeof(float);
    float*  zbuf  = (float*)w;  w += (size_t)B*2*HDIM*sizeof(float);
    double* stats = (double*)w; w += (size_t)2*2*HDIM*sizeof(double);
    float*  ssn   = (float*)w;  w += (size_t)2*HDIM*sizeof(float);
    float*  ssv   = (float*)w;  w += (size_t)2*2*HDIM*sizeof(float);
    int*    cnt   = (int*)w;    w += (size_t)N*sizeof(int);
    int*    coff  = (int*)w;    w += (size_t)(N+1)*sizeof(int);
    int*    fillc = (int*)w;    w += (size_t)N*sizeof(int);
    int*    eid   = (int*)w;    w += (size_t)E*sizeof(int);
    int*    part  = (int*)w;    w += (size_t)512*sizeof(int);
    int*    gstart= (int*)w;    w += (size_t)(B+1)*sizeof(int);
    w = (char*)(((size_t)w + 31) & ~(size_t)31);
    int2*   eaux  = (int2*)w;   w += (size_t)E*sizeof(int2);
    h2v*    efph  = (h2v*)w;    w += (size_t)E*8*sizeof(h2v);
    h2v*    Weh   = (h2v*)w;    w += (size_t)NL*HDIM*8*sizeof(h2v);
    unsigned short* Xb  = (unsigned short*)w; w += (size_t)N*KP1*sizeof(unsigned short);
    unsigned short* Wnb = (unsigned short*)w; w += (size_t)NL*HDIM*KP1*sizeof(unsigned short);
    _Float16* vsumh = (_Float16*)w; w += (size_t)B*KP1*sizeof(_Float16);
    _Float16* zbufh = (_Float16*)w; w += (size_t)B*KP2*sizeof(_Float16);
    _Float16* W1h   = (_Float16*)w; w += (size_t)(NL-1)*2*HDIM*KP1*sizeof(_Float16);
    _Float16* W2h   = (_Float16*)w; w += (size_t)(NL-1)*HDIM*KP2*sizeof(_Float16);

    const int NT = N*HDIM;
    const int BT = B*HDIM;
    auto cdiv = [](int a, int b){ return (a + b - 1)/b; };
    const int nb = cdiv(N, 256);

    // ---- setup: degrees + CSR + permuted edge data + graph ranges ----
    (void)hipMemsetAsync(cnt, 0, (size_t)N*sizeof(int), stream);
    k_count_deg<<<cdiv(E,256),256,0,stream>>>(dst, cnt, E);
    k_deg<<<nb,256,0,stream>>>(cnt, degs, invd, N);
    k_scan_partial<<<nb,256,0,stream>>>(cnt, part, N);
    k_scan_blocks<<<1,512,0,stream>>>(part, nb);
    k_scan_final<<<nb,256,0,stream>>>(cnt, part, coff, N);
    (void)hipMemsetAsync(fillc, 0, (size_t)N*sizeof(int), stream);
    k_fill<<<cdiv(E,256),256,0,stream>>>(dst, coff, fillc, eid, E);
    k_permute<<<cdiv(E,256),256,0,stream>>>(eid, src, dst, degs, edge_feats, eaux, efph, E);
    k_gstart<<<nb,256,0,stream>>>(gid, gstart, N, B);
    // ---- setup: weights, X0 (+ fused layer-0 segment sum) ----
    for (int l = 0; l < NL; l++)
        k_wt<<<cdiv(HDIM*KP1,256),256,0,stream>>>(Wn + (size_t)l*HDIM*HDIM,
                                                  Wnb + (size_t)l*HDIM*KP1, HDIM, HDIM, KP1);
    for (int l = 1; l < NL-1; l++){
        k_wt16<<<cdiv(2*HDIM*KP1,256),256,0,stream>>>(vW1 + (size_t)l*HDIM*2*HDIM,
                                                      W1h + (size_t)l*2*HDIM*KP1, HDIM, 2*HDIM, KP1);
        k_wt16<<<cdiv(HDIM*KP2,256),256,0,stream>>>(vW2 + (size_t)l*2*HDIM*HDIM,
                                                    W2h + (size_t)l*HDIM*KP2, 2*HDIM, HDIM, KP2);
    }
    k_wehalf<<<cdiv(NL*HDIM*8,256),256,0,stream>>>(We, Weh, NL*HDIM*8);
    // fused: Xb0 = bf16(emb[nt] + vn), vsum0 = segsum + vn
    k_x0seg<<<B,KP1,0,stream>>>(node_emb, node_types, vn_emb, gstart, Xb, vsum, vsumh);

    const int nbx = cdiv(HDIM,64);               // 5 col-tiles
    const int ngemm = nbx * cdiv(N,128);         // 1D grid, XCD-swizzled in-kernel
    for (int l = 0; l < NL; l++){
        // hp(fp16) = Xb @ Wn[l] + bn_lin[l]  (XCD-chunked swizzle for A-tile L2 reuse)
        k_gemm_mfma<<<ngemm,256,0,stream>>>(
            Xb, KP1, Wnb + (size_t)l*HDIM*KP1, KP1, bn_lin + (size_t)l*HDIM, hph, N, KP1, HDIM, nbx);
        int mid = (l < NL-1);
        // agg = residual + CSR-aggregated edge messages (fp16 intermediate for mid layers)
        k_agg<<<4096,256,0,stream>>>(hph, res_emb + (size_t)l*HDIM, invd,
                                     efph, eaux, coff,
                                     Weh + (size_t)l*HDIM*8, be + (size_t)l*HDIM,
                                     aggh, out, mid, N);
        // node BN stats (rpb=64 -> 1563 blocks; 4-chain ILP)
        (void)hipMemsetAsync(stats, 0, (size_t)2*HDIM*sizeof(double), stream);
        if (mid)
            k_colstats_h<<<dim3(cdiv(N,64),1),320,0,stream>>>(aggh, N, HDIM, 64, stats);
        else
            k_colstats<<<dim3(cdiv(N,64),1),320,0,stream>>>(out, N, HDIM, 64, stats);
        k_bn_finalize<<<1,320,0,stream>>>(stats, bn_gamma + (size_t)l*HDIM, bn_beta + (size_t)l*HDIM,
                                          HDIM, (float)N, ssn);
        if (l == 0){
            // ---- layer-0 vnode MLP: FULL f32 (rank-1 vsum -> BN sign-sensitivity) ----
            k_gemm<<<dim3(cdiv(B,64), cdiv(2*HDIM,64)),256,0,stream>>>(
                vsum, vW1, vb1, zbuf, B, HDIM, 2*HDIM);
            (void)hipMemsetAsync(stats, 0, (size_t)2*2*HDIM*sizeof(double), stream);
            k_colstats<<<dim3(cdiv(B,32),2),320,0,stream>>>(zbuf, B, 2*HDIM, 32, stats);
            k_bn_finalize<<<1,640,0,stream>>>(stats, vg1, vbt1, 2*HDIM, (float)B, ssv);
            k_bn_apply<2*HDIM><<<cdiv(B*2*HDIM,256),256,0,stream>>>(zbuf, ssv, B*2*HDIM, 1);
            k_gemm<<<dim3(cdiv(B,64), cdiv(HDIM,64)),256,0,stream>>>(
                zbuf, vW2, vb2, vfeat, B, 2*HDIM, HDIM);
            (void)hipMemsetAsync(stats, 0, (size_t)2*HDIM*sizeof(double), stream);
            k_colstats<<<dim3(cdiv(B,32),1),320,0,stream>>>(vfeat, B, HDIM, 32, stats);
            k_bn_finalize<<<1,320,0,stream>>>(stats, vg2, vbt2, HDIM, (float)B, ssv);
            k_bn_apply<HDIM><<<cdiv(BT,256),256,0,stream>>>(vfeat, ssv, BT, 1);
            k_bnvseg<<<B,KP1,0,stream>>>(aggh, ssn, vfeat, gstart, Xb, vsumh, 1);
        } else if (l < NL-1){
            // ---- layers 1..3 vnode MLP: fp16 MFMA (full-rank vsum, concentration-safe) ----
            k_gemm_mfma_h<<<dim3(cdiv(B,128), cdiv(2*HDIM,64)),256,0,stream>>>(
                vsumh, KP1, W1h + (size_t)l*2*HDIM*KP1, KP1, vb1 + (size_t)l*2*HDIM,
                zbuf, B, KP1, 2*HDIM);
            (void)hipMemsetAsync(stats, 0, (size_t)2*2*HDIM*sizeof(double), stream);
            k_colstats<<<dim3(cdiv(B,32),2),320,0,stream>>>(zbuf, B, 2*HDIM, 32, stats);
            k_bn_finalize<<<1,640,0,stream>>>(stats, vg1 + (size_t)l*2*HDIM, vbt1 + (size_t)l*2*HDIM,
                                              2*HDIM, (float)B, ssv);
            k_bn_applyh<2*HDIM, KP2><<<cdiv(B*KP2,256),256,0,stream>>>(zbuf, ssv, zbufh, B);
            k_gemm_mfma_h<<<dim3(cdiv(B,128), cdiv(HDIM,64)),256,0,stream>>>(
                zbufh, KP2, W2h + (size_t)l*HDIM*KP2, KP2, vb2 + (size_t)l*HDIM,
                vfeat, B, KP2, HDIM);
            (void)hipMemsetAsync(stats, 0, (size_t)2*HDIM*sizeof(double), stream);
            k_colstats<<<dim3(cdiv(B,32),1),320,0,stream>>>(vfeat, B, HDIM, 32, stats);
            k_bn_finalize<<<1,320,0,stream>>>(stats, vg2 + (size_t)l*HDIM, vbt2 + (size_t)l*HDIM,
                                              HDIM, (float)B, ssv);
            k_bn_apply<HDIM><<<cdiv(BT,256),256,0,stream>>>(vfeat, ssv, BT, 1);
            k_bnvseg<<<B,KP1,0,stream>>>(aggh, ssn, vfeat, gstart, Xb, vsumh,
                                         (l < NL-2) ? 1 : 0);
        } else {
            k_bn_apply<HDIM><<<cdiv(NT,256),256,0,stream>>>(out, ssn, NT, 0);
        }
    }
}